// Round 13
// baseline (406.778 us; speedup 1.0000x reference)
//
#include <hip/hip_runtime.h>
#include <cmath>
#include <cstddef>

#define B_TOT 32768
#define H_STEPS 256
#define HIDN 128
#define RHIDN 64
#define CHUNK 16

// Param-table grid: soc in [0,1] x 129 rows, t in [-10,58] x 513 cols.
#define SN 129
#define TN 513
#define T_LO   (-10.0f)
#define T_STEP (68.0f/512.0f)
#define T_INV  (512.0f/68.0f)

// Per-wave LDS staging layout (float element offsets), 8 batteries/wave.
#define OFF_V 0        // 8 * 20
#define OFF_P 160      // 8 * 84
#define OFF_S 832      // 8 * 52
#define OFF_I 1248     // 8 * 20
#define OFF_T 1408     // 8 * 20
#define OFF_D 1568     // 64 dump words
#define WREG  1632     // floats per wave = 6528B; x4 waves = 26KB

#define C2L   2.8853900817779268f   // 2*log2(e)  (residual tanh prescale)

typedef float vf2 __attribute__((ext_vector_type(2)));
typedef float vf4 __attribute__((ext_vector_type(4)));

__device__ __forceinline__ float frcp(float x){ return __builtin_amdgcn_rcpf(x); }
__device__ __forceinline__ float fexp2(float x){ return __builtin_amdgcn_exp2f(x); }

__device__ __forceinline__ vf2 splat2(float x){ vf2 r; r.x = x; r.y = x; return r; }
__device__ __forceinline__ vf2 mk2(float a, float b){ vf2 r; r.x = a; r.y = b; return r; }
__device__ __forceinline__ vf2 vfma2(vf2 a, vf2 b, vf2 c){ return __builtin_elementwise_fma(a, b, c); }
__device__ __forceinline__ vf2 prcp2(vf2 x){ vf2 r; r.x = frcp(x.x); r.y = frcp(x.y); return r; }

__device__ __forceinline__ vf4 nt_load4(const float* p){
  return __builtin_nontemporal_load((const vf4*)p);
}
__device__ __forceinline__ void nt_store4(float* p, vf4 v){
  __builtin_nontemporal_store(v, (vf4*)p);
}

// ---------- table build: one thread per (si,ti) cell, libm precision ----------
__global__ __launch_bounds__(256)
void build_tab_kernel(const float* __restrict__ gW1, const float* __restrict__ gb1,
                      const float* __restrict__ gW2, const float* __restrict__ gb2,
                      float* __restrict__ tab)
{
  const int cell = blockIdx.x * 256 + threadIdx.x;
  if (cell >= SN * TN) return;
  const int si = cell / TN, ti = cell - si * TN;
  const float soc = (float)si * (1.0f/128.0f);
  const float t   = T_LO + (float)ti * T_STEP;

  float a0 = gb2[0], a1 = gb2[1], a2 = gb2[2], a3 = gb2[3], a4 = gb2[4];
  for (int j = 0; j < HIDN; ++j){
    float h = tanhf(fmaf(soc, gW1[j], fmaf(t, gW1[HIDN + j], gb1[j])));
    a0 = fmaf(h, gW2[j*5+0], a0);
    a1 = fmaf(h, gW2[j*5+1], a1);
    a2 = fmaf(h, gW2[j*5+2], a2);
    a3 = fmaf(h, gW2[j*5+3], a3);
    a4 = fmaf(h, gW2[j*5+4], a4);
  }
  float p0 = fmaf(fmaxf(a0,0.f) + log1pf(expf(-fabsf(a0))), 0.005f,   1e-6f);
  float p1 = fmaf(fmaxf(a1,0.f) + log1pf(expf(-fabsf(a1))), 0.005f,   1e-6f);
  float p2 = fmaf(fmaxf(a2,0.f) + log1pf(expf(-fabsf(a2))), 2000.0f,  1e-6f);
  float p3 = fmaf(fmaxf(a3,0.f) + log1pf(expf(-fabsf(a3))), 0.005f,   1e-6f);
  float p4 = fmaf(fmaxf(a4,0.f) + log1pf(expf(-fabsf(a4))), 10000.0f, 1e-6f);

  float* c = tab + ((size_t)cell << 3);
  c[0]=p0; c[1]=p1; c[2]=p2; c[3]=p3; c[4]=p4; c[5]=0.f; c[6]=0.f; c[7]=0.f;
}

// ---------- main scan kernel: T=8 lanes/battery (4 waves/SIMD) ----------
__global__ __launch_bounds__(256, 4)
void dcir_node_kernel(const float* __restrict__ gI,
                      const float* __restrict__ gT,
                      const float* __restrict__ gsoc0,
                      const float* __restrict__ gWr1,
                      const float* __restrict__ gbr1,
                      const float* __restrict__ gWr2,
                      const float* __restrict__ gbr2,
                      const float* __restrict__ tab,
                      float* __restrict__ gV,
                      float* __restrict__ gP,
                      float* __restrict__ gS)
{
  // Residual weights pre-paired: lane o (0..7) owns units o*8..o*8+7 = 4 pairs.
  // For fixed (p,g) the 8 role lanes read 8 contiguous 16B slots = all 32
  // banks once -> conflict-free broadcast.
  __shared__ float4 pw[4][4][8];    // [pair][component-group][role]
  __shared__ float  srb;            // sum(Wr2)
  __shared__ __attribute__((aligned(16))) float wsbuf[4][WREG];

  const int tid = threadIdx.x;
  if (tid < 32){
    int o = tid >> 2, p = tid & 3;
    int u0 = o*8 + 2*p, u1 = u0 + 1;
    pw[p][0][o] = make_float4(gWr1[0*RHIDN+u0]*C2L, gWr1[0*RHIDN+u1]*C2L,
                              gWr1[1*RHIDN+u0]*C2L, gWr1[1*RHIDN+u1]*C2L);
    pw[p][1][o] = make_float4(gWr1[2*RHIDN+u0]*C2L, gWr1[2*RHIDN+u1]*C2L,
                              gWr1[3*RHIDN+u0]*C2L, gWr1[3*RHIDN+u1]*C2L);
    pw[p][2][o] = make_float4(gWr1[4*RHIDN+u0]*C2L, gWr1[4*RHIDN+u1]*C2L,
                              gbr1[u0]*C2L,         gbr1[u1]*C2L);
    pw[p][3][o] = make_float4(gWr2[u0], gWr2[u1], 0.0f, 0.0f);
  } else if (tid == 32){
    float s = 0.0f;
    for (int u = 0; u < RHIDN; ++u) s += gWr2[u];
    srb = s;
  }
  __syncthreads();

  const int w    = tid >> 6;
  const int lane = tid & 63;
  const int bq   = lane >> 3;          // battery index within wave (0..7)
  const int o    = lane & 7;           // role lane within octet
  float* __restrict__ ws = wsbuf[w];

  const int wbase = (blockIdx.x * 4 + w) * 8;    // wave's first battery
  const int b = wbase + bq;                      // this lane's battery

  const float rb = srb + gbr2[0];   // residual tanh-fold constant

  float soc = gsoc0[b];
  vf2 vcp = splat2(0.0f);           // {vc1, vc2}

  // Per-role staging slots (R5 octet assignment: 1-2 scalar writes/lane/step).
  int baseA, baseB;
  {
    baseA = (o == 0) ? OFF_V + bq*20
          : (o <= 5) ? OFF_P + bq*84 + (o-1)
                     : OFF_S + bq*52 + (o-6);
    baseB = (o == 0) ? OFF_S + bq*52 + 2 : OFF_D + lane;
  }
  const int strA = (o == 0) ? 1 : ((o <= 5) ? 5 : 3);
  const int strB = (o == 0) ? 3 : 0;

  for (int c0 = 0; c0 < H_STEPS; c0 += CHUNK){
    // ---- stage input chunk: 32 float4 per array; lanes<32 do I, >=32 do T
    {
      int s = lane & 31;
      int bw = s >> 2, sub = s & 3;
      int gb = wbase + bw;
      if (lane < 32){
        vf4 iv = nt_load4(gI + (size_t)gb*H_STEPS + c0 + sub*4);
        *(vf4*)&ws[OFF_I + bw*20 + sub*4] = iv;
      } else {
        vf4 tv = nt_load4(gT + (size_t)gb*H_STEPS + c0 + sub*4);
        *(vf4*)&ws[OFF_T + bw*20 + sub*4] = tv;
      }
    }
    __builtin_amdgcn_wave_barrier();

    // rotated ik/tk: LDS read issued one step ahead
    float ikc = ws[OFF_I + bq*20 + 0];
    float tkc = ws[OFF_T + bq*20 + 0];

    #pragma unroll 1
    for (int kk = 0; kk < CHUNK; ++kk){
      const float ik = ikc, tk = tkc;
      {
        int kn = (kk + 1 < CHUNK) ? kk + 1 : kk;
        ikc = ws[OFF_I + bq*20 + kn];
        tkc = ws[OFF_T + bq*20 + kn];
      }

      // ---- (1) index calc + ISSUE table loads (consumed after the MLP)
      float tq = fminf(fmaxf((tk - T_LO) * T_INV, 0.0f), 511.999f);
      int   ti = (int)tq; float tf = tq - (float)ti;
      float sq = fminf(soc * 128.0f, 127.999f);
      int   si = (int)sq; float sf = sq - (float)si;
      const float* c = tab + (size_t)((si*TN + ti) << 3);
      vf4 q00 = *(const vf4*)(c);
      vf4 q01 = *(const vf4*)(c + 8);
      vf4 q10 = *(const vf4*)(c + 8*TN);
      vf4 q11 = *(const vf4*)(c + 8*TN + 8);
      float e00 = c[4], e01 = c[12], e10 = c[8*TN + 4], e11 = c[8*TN + 12];

      // ---- (2) residual MLP: 4 unit-pairs/lane, packed
      vf2 ra2 = splat2(0.0f);
      const vf2 vc1s = splat2(vcp.x), vc2s = splat2(vcp.y);
      const vf2 socs = splat2(soc), iks = splat2(ik), tks = splat2(tk);
      #pragma unroll
      for (int p = 0; p < 4; ++p){
        const float4 c0w = pw[p][0][o];
        const float4 c1w = pw[p][1][o];
        const float4 c2w = pw[p][2][o];
        const float4 c3w = pw[p][3][o];
        vf2 arg = vfma2(vc1s, mk2(c0w.x, c0w.y),
                  vfma2(vc2s, mk2(c0w.z, c0w.w),
                  vfma2(socs, mk2(c1w.x, c1w.y),
                  vfma2(iks,  mk2(c1w.z, c1w.w),
                  vfma2(tks,  mk2(c2w.x, c2w.y), mk2(c2w.z, c2w.w))))));
        vf2 e; e.x = fexp2(arg.x); e.y = fexp2(arg.y);
        vf2 r = prcp2(e + 1.0f);
        ra2 = vfma2(r, mk2(c3w.x, c3w.y), ra2);
      }
      float ra = ra2.x + ra2.y;
      ra += __shfl_xor(ra, 1, 8);
      ra += __shfl_xor(ra, 2, 8);
      ra += __shfl_xor(ra, 4, 8);

      // ---- (3) bilinear interp, (R0,R1) and (C1,R2) packed; C2 scalar
      float R0, R1, C1, R2, C2;
      {
        vf2 a00 = mk2(q00.x, q00.y), a01 = mk2(q01.x, q01.y);
        vf2 a10 = mk2(q10.x, q10.y), a11 = mk2(q11.x, q11.y);
        vf2 b00 = mk2(q00.z, q00.w), b01 = mk2(q01.z, q01.w);
        vf2 b10 = mk2(q10.z, q10.w), b11 = mk2(q11.z, q11.w);
        const vf2 tfs = splat2(tf), sfs = splat2(sf);
        vf2 v0 = vfma2(tfs, a01 - a00, a00);
        vf2 v1 = vfma2(tfs, a11 - a10, a10);
        vf2 RA = vfma2(sfs, v1 - v0, v0);          // {R0, R1}
        v0 = vfma2(tfs, b01 - b00, b00);
        v1 = vfma2(tfs, b11 - b10, b10);
        vf2 RB = vfma2(sfs, v1 - v0, v0);          // {C1, R2}
        float s0 = fmaf(tf, e01 - e00, e00);
        float s1 = fmaf(tf, e11 - e10, e10);
        C2 = fmaf(sf, s1 - s0, s0);
        R0 = RA.x; R1 = RA.y; C1 = RB.x; R2 = RB.y;
      }

      const float res = fmaf(-2.0f, ra, rb) * 0.01f;
      const float ocv = fmaf(1.2f, soc, 3.0f) - 0.4f * fexp2(-17.312340490667562f * soc);
      const float Vp  = ocv - R0 * ik - vcp.x - vcp.y + res;

      // ---- stage outputs for step k (pre-update state), R5 octet role split
      {
        float vA = (o==0) ? Vp
                 : (o==1) ? R0 : (o==2) ? R1 : (o==3) ? C1
                 : (o==4) ? R2 : (o==5) ? C2
                 : (o==6) ? vcp.x : vcp.y;
        ws[baseA + kk*strA] = vA;
        ws[baseB + kk*strB] = soc;   // meaningful only for o==0 (S col 2)
      }

      // ---- RK4 folded: vc += (A - K*vc) * phi(K), phi = 1-K/2+K^2/6-K^3/24
      {
        vf2 iC = prcp2(mk2(C1, C2));
        vf2 A  = splat2(ik) * iC;
        vf2 K  = prcp2(mk2(R1 * C1, R2 * C2));
        vf2 phi = vfma2(K, vfma2(K, vfma2(K, splat2(-1.0f/24.0f), splat2(1.0f/6.0f)),
                                 splat2(-0.5f)), splat2(1.0f));
        vf2 k1 = vfma2(-K, vcp, A);
        vcp = vfma2(k1, phi, vcp);
      }

      soc = soc - ik * (1.0f/10800.0f);
      soc = fminf(fmaxf(soc, 0.0f), 1.0f);
    }
    __builtin_amdgcn_wave_barrier();

    // ---- writeback (non-temporal, contiguous per battery)
    // V: 32 float4 (8 bat x 4), lanes < 32
    if (lane < 32){
      int bw = lane >> 2, sub = lane & 3;
      vf4 v = *(vf4*)&ws[OFF_V + bw*20 + sub*4];
      nt_store4(gV + (size_t)(wbase + bw)*H_STEPS + c0 + sub*4, v);
    }
    // P: 160 float4 (8 bat x 20): 2 full rounds + 1 half round
    #pragma unroll
    for (int r = 0; r < 3; ++r){
      int s = lane + r*64;
      if (s < 160){
        int bw = s / 20, sub = s % 20;
        vf4 v = *(vf4*)&ws[OFF_P + bw*84 + sub*4];
        nt_store4(gP + (size_t)(wbase + bw)*H_STEPS*5 + (size_t)c0*5 + sub*4, v);
      }
    }
    // S: 96 float4 (8 bat x 12): 1 full + 1 half round
    #pragma unroll
    for (int r = 0; r < 2; ++r){
      int s = lane + r*64;
      if (s < 96){
        int bw = s / 12, sub = s % 12;
        vf4 v = *(vf4*)&ws[OFF_S + bw*52 + sub*4];
        nt_store4(gS + (size_t)(wbase + bw)*H_STEPS*3 + (size_t)c0*3 + sub*4, v);
      }
    }
    __builtin_amdgcn_wave_barrier();
  }
}

extern "C" void kernel_launch(void* const* d_in, const int* in_sizes, int n_in,
                              void* d_out, int out_size, void* d_ws, size_t ws_size,
                              hipStream_t stream)
{
  // setup_inputs order: V, I, Tz, soc0, W1, b1, W2, b2, Wr1, br1, Wr2, br2
  const float* gI   = (const float*)d_in[1];
  const float* gT   = (const float*)d_in[2];
  const float* gs0  = (const float*)d_in[3];
  const float* gW1  = (const float*)d_in[4];
  const float* gb1  = (const float*)d_in[5];
  const float* gW2  = (const float*)d_in[6];
  const float* gb2  = (const float*)d_in[7];
  const float* gWr1 = (const float*)d_in[8];
  const float* gbr1 = (const float*)d_in[9];
  const float* gWr2 = (const float*)d_in[10];
  const float* gbr2 = (const float*)d_in[11];

  float* gV = (float*)d_out;                                  // (B,H)
  float* gP = gV + (size_t)B_TOT * H_STEPS;                   // (B,H,5)
  float* gS = gP + (size_t)B_TOT * H_STEPS * 5;               // (B,H,3)

  float* tab = (float*)d_ws;   // 129*513*8 floats = 2.12MB of workspace

  {
    int cells = SN * TN;
    dim3 bgrid((cells + 255) / 256), bblock(256);
    hipLaunchKernelGGL(build_tab_kernel, bgrid, bblock, 0, stream,
                       gW1, gb1, gW2, gb2, tab);
  }
  // T=8, G=1: 8 bat/wave, 1024 blocks, 4 waves/SIMD
  dim3 grid(B_TOT / 32);
  dim3 block(256);
  hipLaunchKernelGGL(dcir_node_kernel, grid, block, 0, stream,
                     gI, gT, gs0, gWr1, gbr1, gWr2, gbr2, tab,
                     gV, gP, gS);
}

// Round 14
// 301.278 us; speedup vs baseline: 1.3502x; 1.3502x over previous
//
#include <hip/hip_runtime.h>
#include <cmath>
#include <cstddef>

#define B_TOT 32768
#define H_STEPS 256
#define HIDN 128
#define RHIDN 64
#define CHUNK 16

// Param-table grid: soc in [0,1] x 129 rows, t in [-10,58] x 513 cols.
#define SN 129
#define TN 513
#define T_LO   (-10.0f)
#define T_STEP (68.0f/512.0f)
#define T_INV  (512.0f/68.0f)

// Per-wave LDS staging layout (float element offsets), known good since R5.
#define OFF_V 0        // 16 * 20
#define OFF_P 320      // 16 * 84
#define OFF_S 1664     // 16 * 52
#define OFF_I 2496     // 16 * 20
#define OFF_T 2816     // 16 * 20
#define OFF_D 3136     // 64 dump words
#define WREG  3200     // floats per wave = 12.8KB; x4 waves = 51.2KB

#define C2L   2.8853900817779268f   // 2*log2(e)  (residual tanh prescale)

typedef float vf2 __attribute__((ext_vector_type(2)));
typedef float vf4 __attribute__((ext_vector_type(4)));

__device__ __forceinline__ float frcp(float x){ return __builtin_amdgcn_rcpf(x); }
__device__ __forceinline__ float fexp2(float x){ return __builtin_amdgcn_exp2f(x); }

__device__ __forceinline__ vf2 splat2(float x){ vf2 r; r.x = x; r.y = x; return r; }
__device__ __forceinline__ vf2 mk2(float a, float b){ vf2 r; r.x = a; r.y = b; return r; }
__device__ __forceinline__ vf2 vfma2(vf2 a, vf2 b, vf2 c){ return __builtin_elementwise_fma(a, b, c); }
__device__ __forceinline__ vf2 prcp2(vf2 x){ vf2 r; r.x = frcp(x.x); r.y = frcp(x.y); return r; }

__device__ __forceinline__ vf4 nt_load4(const float* p){
  return __builtin_nontemporal_load((const vf4*)p);
}
__device__ __forceinline__ void nt_store4(float* p, vf4 v){
  __builtin_nontemporal_store(v, (vf4*)p);
}

// ---------- table build: one thread per (si,ti) cell, libm precision ----------
__global__ __launch_bounds__(256)
void build_tab_kernel(const float* __restrict__ gW1, const float* __restrict__ gb1,
                      const float* __restrict__ gW2, const float* __restrict__ gb2,
                      float* __restrict__ tab)
{
  const int cell = blockIdx.x * 256 + threadIdx.x;
  if (cell >= SN * TN) return;
  const int si = cell / TN, ti = cell - si * TN;
  const float soc = (float)si * (1.0f/128.0f);
  const float t   = T_LO + (float)ti * T_STEP;

  float a0 = gb2[0], a1 = gb2[1], a2 = gb2[2], a3 = gb2[3], a4 = gb2[4];
  for (int j = 0; j < HIDN; ++j){
    float h = tanhf(fmaf(soc, gW1[j], fmaf(t, gW1[HIDN + j], gb1[j])));
    a0 = fmaf(h, gW2[j*5+0], a0);
    a1 = fmaf(h, gW2[j*5+1], a1);
    a2 = fmaf(h, gW2[j*5+2], a2);
    a3 = fmaf(h, gW2[j*5+3], a3);
    a4 = fmaf(h, gW2[j*5+4], a4);
  }
  float p0 = fmaf(fmaxf(a0,0.f) + log1pf(expf(-fabsf(a0))), 0.005f,   1e-6f);
  float p1 = fmaf(fmaxf(a1,0.f) + log1pf(expf(-fabsf(a1))), 0.005f,   1e-6f);
  float p2 = fmaf(fmaxf(a2,0.f) + log1pf(expf(-fabsf(a2))), 2000.0f,  1e-6f);
  float p3 = fmaf(fmaxf(a3,0.f) + log1pf(expf(-fabsf(a3))), 0.005f,   1e-6f);
  float p4 = fmaf(fmaxf(a4,0.f) + log1pf(expf(-fabsf(a4))), 10000.0f, 1e-6f);

  float* c = tab + ((size_t)cell << 3);
  c[0]=p0; c[1]=p1; c[2]=p2; c[3]=p3; c[4]=p4; c[5]=0.f; c[6]=0.f; c[7]=0.f;
}

// ---------- main scan kernel: T=4, weights held in VGPRs (256-reg budget) ----------
__global__ __launch_bounds__(256)
__attribute__((amdgpu_waves_per_eu(2)))
void dcir_node_kernel(const float* __restrict__ gI,
                      const float* __restrict__ gT,
                      const float* __restrict__ gsoc0,
                      const float* __restrict__ gWr1,
                      const float* __restrict__ gbr1,
                      const float* __restrict__ gWr2,
                      const float* __restrict__ gbr2,
                      const float* __restrict__ tab,
                      float* __restrict__ gV,
                      float* __restrict__ gP,
                      float* __restrict__ gS)
{
  // Residual weights staged pre-paired in LDS once, then hoisted to VGPRs.
  __shared__ float4 pw[8][4][4];    // [pair][component-group][role]
  __shared__ float  srb;            // sum(Wr2)
  __shared__ __attribute__((aligned(16))) float wsbuf[4][WREG];

  const int tid = threadIdx.x;
  if (tid < 32){
    int o = tid >> 3, p = tid & 7;
    int u0 = o*16 + 2*p, u1 = u0 + 1;
    pw[p][0][o] = make_float4(gWr1[0*RHIDN+u0]*C2L, gWr1[0*RHIDN+u1]*C2L,
                              gWr1[1*RHIDN+u0]*C2L, gWr1[1*RHIDN+u1]*C2L);
    pw[p][1][o] = make_float4(gWr1[2*RHIDN+u0]*C2L, gWr1[2*RHIDN+u1]*C2L,
                              gWr1[3*RHIDN+u0]*C2L, gWr1[3*RHIDN+u1]*C2L);
    pw[p][2][o] = make_float4(gWr1[4*RHIDN+u0]*C2L, gWr1[4*RHIDN+u1]*C2L,
                              gbr1[u0]*C2L,         gbr1[u1]*C2L);
    pw[p][3][o] = make_float4(gWr2[u0], gWr2[u1], 0.0f, 0.0f);
  } else if (tid == 32){
    float s = 0.0f;
    for (int u = 0; u < RHIDN; ++u) s += gWr2[u];
    srb = s;
  }
  __syncthreads();

  const int w    = tid >> 6;
  const int lane = tid & 63;
  const int bq   = lane >> 2;          // battery index within wave (0..15)
  const int o    = lane & 3;           // role lane within quad
  float* __restrict__ ws = wsbuf[w];

  const int wbase = (blockIdx.x * 4 + w) * 16;   // wave's first battery
  const int b = wbase + bq;                      // this lane's battery

  const float rb = srb + gbr2[0];   // residual tanh-fold constant

  // ---- hoist this lane's weights LDS -> VGPRs (one-time; 112 VGPR).
  // Requires the 256-reg budget from amdgpu_waves_per_eu(2): under
  // launch_bounds(256,2)'s 128-reg cap the compiler rematerializes these
  // as in-loop LDS reads (R12 null result), leaving the kernel bound on
  // the LDS read pipe (~330us/CU of ds_read_b128 broadcasts).
  vf2 Wv1[8], Wv2[8], Wsc[8], Wik[8], Wtk[8], Wbb[8], Wo[8];
  #pragma unroll
  for (int p = 0; p < 8; ++p){
    const float4 c0w = pw[p][0][o];
    const float4 c1w = pw[p][1][o];
    const float4 c2w = pw[p][2][o];
    const float4 c3w = pw[p][3][o];
    Wv1[p] = mk2(c0w.x, c0w.y);
    Wv2[p] = mk2(c0w.z, c0w.w);
    Wsc[p] = mk2(c1w.x, c1w.y);
    Wik[p] = mk2(c1w.z, c1w.w);
    Wtk[p] = mk2(c2w.x, c2w.y);
    Wbb[p] = mk2(c2w.z, c2w.w);
    Wo[p]  = mk2(c3w.x, c3w.y);
  }

  float soc = gsoc0[b];
  vf2 vcp = splat2(0.0f);           // {vc1, vc2}

  // Per-role staging slots (R1 quad assignment: 3 scalar writes/lane/step).
  int baseA, baseB, baseC;
  {
    if      (o == 0){ baseA = OFF_V + bq*20;     baseB = OFF_S + bq*52;     baseC = OFF_D + lane; }
    else if (o == 1){ baseA = OFF_P + bq*84 + 0; baseB = OFF_P + bq*84 + 1; baseC = OFF_S + bq*52 + 1; }
    else if (o == 2){ baseA = OFF_P + bq*84 + 2; baseB = OFF_P + bq*84 + 3; baseC = OFF_S + bq*52 + 2; }
    else            { baseA = OFF_P + bq*84 + 4; baseB = OFF_D + lane;      baseC = OFF_D + lane; }
  }
  const int strA = (o == 0) ? 1 : 5;
  const int strB = (o == 0) ? 3 : ((o == 3) ? 0 : 5);
  const int strC = (o == 1 || o == 2) ? 3 : 0;

  for (int c0 = 0; c0 < H_STEPS; c0 += CHUNK){
    // ---- stage input chunk: 64 float4 per array per wave (1 per lane)
    {
      int bw = lane >> 2, sub = lane & 3;
      int gb = wbase + bw;
      vf4 iv = nt_load4(gI + (size_t)gb*H_STEPS + c0 + sub*4);
      vf4 tv = nt_load4(gT + (size_t)gb*H_STEPS + c0 + sub*4);
      *(vf4*)&ws[OFF_I + bw*20 + sub*4] = iv;
      *(vf4*)&ws[OFF_T + bw*20 + sub*4] = tv;
    }
    __builtin_amdgcn_wave_barrier();

    // rotated ik/tk: LDS read issued one step ahead
    float ikc = ws[OFF_I + bq*20 + 0];
    float tkc = ws[OFF_T + bq*20 + 0];

    #pragma unroll 1
    for (int kk = 0; kk < CHUNK; ++kk){
      const float ik = ikc, tk = tkc;
      {
        int kn = (kk + 1 < CHUNK) ? kk + 1 : kk;
        ikc = ws[OFF_I + bq*20 + kn];
        tkc = ws[OFF_T + bq*20 + kn];
      }

      // ---- (1) index calc + ISSUE table loads (consumed after the MLP)
      float tq = fminf(fmaxf((tk - T_LO) * T_INV, 0.0f), 511.999f);
      int   ti = (int)tq; float tf = tq - (float)ti;
      float sq = fminf(soc * 128.0f, 127.999f);
      int   si = (int)sq; float sf = sq - (float)si;
      const float* c = tab + (size_t)((si*TN + ti) << 3);
      vf4 q00 = *(const vf4*)(c);
      vf4 q01 = *(const vf4*)(c + 8);
      vf4 q10 = *(const vf4*)(c + 8*TN);
      vf4 q11 = *(const vf4*)(c + 8*TN + 8);
      float e00 = c[4], e01 = c[12], e10 = c[8*TN + 4], e11 = c[8*TN + 12];

      // ---- (2) residual MLP, unit-pairs packed, weights in VGPRs (no LDS)
      vf2 ra2 = splat2(0.0f);
      const vf2 vc1s = splat2(vcp.x), vc2s = splat2(vcp.y);
      const vf2 socs = splat2(soc), iks = splat2(ik), tks = splat2(tk);
      #pragma unroll
      for (int p = 0; p < 8; ++p){
        vf2 arg = vfma2(vc1s, Wv1[p],
                  vfma2(vc2s, Wv2[p],
                  vfma2(socs, Wsc[p],
                  vfma2(iks,  Wik[p],
                  vfma2(tks,  Wtk[p], Wbb[p])))));
        vf2 e; e.x = fexp2(arg.x); e.y = fexp2(arg.y);
        vf2 r = prcp2(e + 1.0f);
        ra2 = vfma2(r, Wo[p], ra2);
      }
      float ra = ra2.x + ra2.y;
      ra += __shfl_xor(ra, 1, 4);
      ra += __shfl_xor(ra, 2, 4);

      // ---- (3) bilinear interp, (R0,R1) and (C1,R2) packed; C2 scalar
      float R0, R1, C1, R2, C2;
      {
        vf2 a00 = mk2(q00.x, q00.y), a01 = mk2(q01.x, q01.y);
        vf2 a10 = mk2(q10.x, q10.y), a11 = mk2(q11.x, q11.y);
        vf2 b00 = mk2(q00.z, q00.w), b01 = mk2(q01.z, q01.w);
        vf2 b10 = mk2(q10.z, q10.w), b11 = mk2(q11.z, q11.w);
        const vf2 tfs = splat2(tf), sfs = splat2(sf);
        vf2 v0 = vfma2(tfs, a01 - a00, a00);
        vf2 v1 = vfma2(tfs, a11 - a10, a10);
        vf2 RA = vfma2(sfs, v1 - v0, v0);          // {R0, R1}
        v0 = vfma2(tfs, b01 - b00, b00);
        v1 = vfma2(tfs, b11 - b10, b10);
        vf2 RB = vfma2(sfs, v1 - v0, v0);          // {C1, R2}
        float s0 = fmaf(tf, e01 - e00, e00);
        float s1 = fmaf(tf, e11 - e10, e10);
        C2 = fmaf(sf, s1 - s0, s0);
        R0 = RA.x; R1 = RA.y; C1 = RB.x; R2 = RB.y;
      }

      const float res = fmaf(-2.0f, ra, rb) * 0.01f;
      const float ocv = fmaf(1.2f, soc, 3.0f) - 0.4f * fexp2(-17.312340490667562f * soc);
      const float Vp  = ocv - R0 * ik - vcp.x - vcp.y + res;

      // ---- stage outputs for step k (pre-update state), R1 role split
      {
        float vA = (o==0) ? Vp    : (o==1) ? R0 : (o==2) ? C1 : C2;
        float vB = (o==0) ? vcp.x : (o==1) ? R1 : R2;
        float vC = (o==1) ? vcp.y : soc;
        ws[baseA + kk*strA] = vA;
        ws[baseB + kk*strB] = vB;
        ws[baseC + kk*strC] = vC;
      }

      // ---- RK4 folded: vc += (A - K*vc) * phi(K), phi = 1-K/2+K^2/6-K^3/24
      {
        vf2 iC = prcp2(mk2(C1, C2));
        vf2 A  = splat2(ik) * iC;
        vf2 K  = prcp2(mk2(R1 * C1, R2 * C2));
        vf2 phi = vfma2(K, vfma2(K, vfma2(K, splat2(-1.0f/24.0f), splat2(1.0f/6.0f)),
                                 splat2(-0.5f)), splat2(1.0f));
        vf2 k1 = vfma2(-K, vcp, A);
        vcp = vfma2(k1, phi, vcp);
      }

      soc = soc - ik * (1.0f/10800.0f);
      soc = fminf(fmaxf(soc, 0.0f), 1.0f);
    }
    __builtin_amdgcn_wave_barrier();

    // ---- writeback (non-temporal, contiguous per battery)
    {
      int bw = lane >> 2, sub = lane & 3;
      vf4 v = *(vf4*)&ws[OFF_V + bw*20 + sub*4];
      nt_store4(gV + (size_t)(wbase + bw)*H_STEPS + c0 + sub*4, v);
    }
    #pragma unroll
    for (int r = 0; r < 5; ++r){
      int s = lane + r*64;
      int bw = s / 20, sub = s % 20;
      vf4 v = *(vf4*)&ws[OFF_P + bw*84 + sub*4];
      nt_store4(gP + (size_t)(wbase + bw)*H_STEPS*5 + (size_t)c0*5 + sub*4, v);
    }
    #pragma unroll
    for (int r = 0; r < 3; ++r){
      int s = lane + r*64;
      int bw = s / 12, sub = s % 12;
      vf4 v = *(vf4*)&ws[OFF_S + bw*52 + sub*4];
      nt_store4(gS + (size_t)(wbase + bw)*H_STEPS*3 + (size_t)c0*3 + sub*4, v);
    }
    __builtin_amdgcn_wave_barrier();
  }
}

extern "C" void kernel_launch(void* const* d_in, const int* in_sizes, int n_in,
                              void* d_out, int out_size, void* d_ws, size_t ws_size,
                              hipStream_t stream)
{
  // setup_inputs order: V, I, Tz, soc0, W1, b1, W2, b2, Wr1, br1, Wr2, br2
  const float* gI   = (const float*)d_in[1];
  const float* gT   = (const float*)d_in[2];
  const float* gs0  = (const float*)d_in[3];
  const float* gW1  = (const float*)d_in[4];
  const float* gb1  = (const float*)d_in[5];
  const float* gW2  = (const float*)d_in[6];
  const float* gb2  = (const float*)d_in[7];
  const float* gWr1 = (const float*)d_in[8];
  const float* gbr1 = (const float*)d_in[9];
  const float* gWr2 = (const float*)d_in[10];
  const float* gbr2 = (const float*)d_in[11];

  float* gV = (float*)d_out;                                  // (B,H)
  float* gP = gV + (size_t)B_TOT * H_STEPS;                   // (B,H,5)
  float* gS = gP + (size_t)B_TOT * H_STEPS * 5;               // (B,H,3)

  float* tab = (float*)d_ws;   // 129*513*8 floats = 2.12MB of workspace

  {
    int cells = SN * TN;
    dim3 bgrid((cells + 255) / 256), bblock(256);
    hipLaunchKernelGGL(build_tab_kernel, bgrid, bblock, 0, stream,
                       gW1, gb1, gW2, gb2, tab);
  }
  dim3 grid(B_TOT / 64);   // T=4,G=1: 16 bat/wave, 512 blocks, 2 waves/SIMD
  dim3 block(256);
  hipLaunchKernelGGL(dcir_node_kernel, grid, block, 0, stream,
                     gI, gT, gs0, gWr1, gbr1, gWr2, gbr2, tab,
                     gV, gP, gS);
}

// Round 15
// 297.353 us; speedup vs baseline: 1.3680x; 1.0132x over previous
//
#include <hip/hip_runtime.h>
#include <cmath>
#include <cstddef>

#define B_TOT 32768
#define H_STEPS 256
#define HIDN 128
#define RHIDN 64
#define CHUNK 16

// Param-table grid: soc in [0,1] x 129 rows, t in [-10,58] x 513 cols.
#define SN 129
#define TN 513
#define T_LO   (-10.0f)
#define T_STEP (68.0f/512.0f)
#define T_INV  (512.0f/68.0f)

// Per-wave LDS staging layout (float element offsets), known good since R5.
#define OFF_V 0        // 16 * 20
#define OFF_P 320      // 16 * 84
#define OFF_S 1664     // 16 * 52
#define OFF_I 2496     // 16 * 20
#define OFF_T 2816     // 16 * 20
#define OFF_D 3136     // 64 dump words
#define WREG  3200     // floats per wave = 12.8KB; x4 waves = 51.2KB

#define C2L   2.8853900817779268f   // 2*log2(e)  (residual tanh prescale)

typedef float vf2 __attribute__((ext_vector_type(2)));
typedef float vf4 __attribute__((ext_vector_type(4)));

__device__ __forceinline__ float frcp(float x){ return __builtin_amdgcn_rcpf(x); }
__device__ __forceinline__ float fexp2(float x){ return __builtin_amdgcn_exp2f(x); }

__device__ __forceinline__ vf2 splat2(float x){ vf2 r; r.x = x; r.y = x; return r; }
__device__ __forceinline__ vf2 mk2(float a, float b){ vf2 r; r.x = a; r.y = b; return r; }
__device__ __forceinline__ vf2 vfma2(vf2 a, vf2 b, vf2 c){ return __builtin_elementwise_fma(a, b, c); }
__device__ __forceinline__ vf2 prcp2(vf2 x){ vf2 r; r.x = frcp(x.x); r.y = frcp(x.y); return r; }

// Opaque register pin: asm output is an un-rematerializable def, so the
// compiler MUST keep the value resident in VGPRs (defeats its heuristic of
// re-reading loop-invariant weights from LDS every iteration — R12/R14 nulls).
__device__ __forceinline__ vf2 pin2(vf2 x){
  double d = __builtin_bit_cast(double, x);
  asm volatile("" : "+v"(d));
  return __builtin_bit_cast(vf2, d);
}

__device__ __forceinline__ vf4 nt_load4(const float* p){
  return __builtin_nontemporal_load((const vf4*)p);
}
__device__ __forceinline__ void nt_store4(float* p, vf4 v){
  __builtin_nontemporal_store(v, (vf4*)p);
}

// ---------- table build: one thread per (si,ti) cell, libm precision ----------
__global__ __launch_bounds__(256)
void build_tab_kernel(const float* __restrict__ gW1, const float* __restrict__ gb1,
                      const float* __restrict__ gW2, const float* __restrict__ gb2,
                      float* __restrict__ tab)
{
  const int cell = blockIdx.x * 256 + threadIdx.x;
  if (cell >= SN * TN) return;
  const int si = cell / TN, ti = cell - si * TN;
  const float soc = (float)si * (1.0f/128.0f);
  const float t   = T_LO + (float)ti * T_STEP;

  float a0 = gb2[0], a1 = gb2[1], a2 = gb2[2], a3 = gb2[3], a4 = gb2[4];
  for (int j = 0; j < HIDN; ++j){
    float h = tanhf(fmaf(soc, gW1[j], fmaf(t, gW1[HIDN + j], gb1[j])));
    a0 = fmaf(h, gW2[j*5+0], a0);
    a1 = fmaf(h, gW2[j*5+1], a1);
    a2 = fmaf(h, gW2[j*5+2], a2);
    a3 = fmaf(h, gW2[j*5+3], a3);
    a4 = fmaf(h, gW2[j*5+4], a4);
  }
  float p0 = fmaf(fmaxf(a0,0.f) + log1pf(expf(-fabsf(a0))), 0.005f,   1e-6f);
  float p1 = fmaf(fmaxf(a1,0.f) + log1pf(expf(-fabsf(a1))), 0.005f,   1e-6f);
  float p2 = fmaf(fmaxf(a2,0.f) + log1pf(expf(-fabsf(a2))), 2000.0f,  1e-6f);
  float p3 = fmaf(fmaxf(a3,0.f) + log1pf(expf(-fabsf(a3))), 0.005f,   1e-6f);
  float p4 = fmaf(fmaxf(a4,0.f) + log1pf(expf(-fabsf(a4))), 10000.0f, 1e-6f);

  float* c = tab + ((size_t)cell << 3);
  c[0]=p0; c[1]=p1; c[2]=p2; c[3]=p3; c[4]=p4; c[5]=0.f; c[6]=0.f; c[7]=0.f;
}

// ---------- main scan kernel: T=4, weights pinned in VGPRs ----------
__global__ __launch_bounds__(256)
__attribute__((amdgpu_waves_per_eu(2, 2)))
void dcir_node_kernel(const float* __restrict__ gI,
                      const float* __restrict__ gT,
                      const float* __restrict__ gsoc0,
                      const float* __restrict__ gWr1,
                      const float* __restrict__ gbr1,
                      const float* __restrict__ gWr2,
                      const float* __restrict__ gbr2,
                      const float* __restrict__ tab,
                      float* __restrict__ gV,
                      float* __restrict__ gP,
                      float* __restrict__ gS)
{
  // Residual weights staged pre-paired in LDS once, then hoisted to VGPRs.
  __shared__ float4 pw[8][4][4];    // [pair][component-group][role]
  __shared__ float  srb;            // sum(Wr2)
  __shared__ __attribute__((aligned(16))) float wsbuf[4][WREG];

  const int tid = threadIdx.x;
  if (tid < 32){
    int o = tid >> 3, p = tid & 7;
    int u0 = o*16 + 2*p, u1 = u0 + 1;
    pw[p][0][o] = make_float4(gWr1[0*RHIDN+u0]*C2L, gWr1[0*RHIDN+u1]*C2L,
                              gWr1[1*RHIDN+u0]*C2L, gWr1[1*RHIDN+u1]*C2L);
    pw[p][1][o] = make_float4(gWr1[2*RHIDN+u0]*C2L, gWr1[2*RHIDN+u1]*C2L,
                              gWr1[3*RHIDN+u0]*C2L, gWr1[3*RHIDN+u1]*C2L);
    pw[p][2][o] = make_float4(gWr1[4*RHIDN+u0]*C2L, gWr1[4*RHIDN+u1]*C2L,
                              gbr1[u0]*C2L,         gbr1[u1]*C2L);
    pw[p][3][o] = make_float4(gWr2[u0], gWr2[u1], 0.0f, 0.0f);
  } else if (tid == 32){
    float s = 0.0f;
    for (int u = 0; u < RHIDN; ++u) s += gWr2[u];
    srb = s;
  }
  __syncthreads();

  const int w    = tid >> 6;
  const int lane = tid & 63;
  const int bq   = lane >> 2;          // battery index within wave (0..15)
  const int o    = lane & 3;           // role lane within quad
  float* __restrict__ ws = wsbuf[w];

  const int wbase = (blockIdx.x * 4 + w) * 16;   // wave's first battery
  const int b = wbase + bq;                      // this lane's battery

  const float rb = srb + gbr2[0];   // residual tanh-fold constant

  // ---- hoist this lane's weights LDS -> VGPRs and PIN them (112 VGPR)
  vf2 Wv1[8], Wv2[8], Wsc[8], Wik[8], Wtk[8], Wbb[8], Wo[8];
  #pragma unroll
  for (int p = 0; p < 8; ++p){
    const float4 c0w = pw[p][0][o];
    const float4 c1w = pw[p][1][o];
    const float4 c2w = pw[p][2][o];
    const float4 c3w = pw[p][3][o];
    Wv1[p] = pin2(mk2(c0w.x, c0w.y));
    Wv2[p] = pin2(mk2(c0w.z, c0w.w));
    Wsc[p] = pin2(mk2(c1w.x, c1w.y));
    Wik[p] = pin2(mk2(c1w.z, c1w.w));
    Wtk[p] = pin2(mk2(c2w.x, c2w.y));
    Wbb[p] = pin2(mk2(c2w.z, c2w.w));
    Wo[p]  = pin2(mk2(c3w.x, c3w.y));
  }

  float soc = gsoc0[b];
  vf2 vcp = splat2(0.0f);           // {vc1, vc2}

  // Per-role staging slots (R1 quad assignment: 3 scalar writes/lane/step).
  int baseA, baseB, baseC;
  {
    if      (o == 0){ baseA = OFF_V + bq*20;     baseB = OFF_S + bq*52;     baseC = OFF_D + lane; }
    else if (o == 1){ baseA = OFF_P + bq*84 + 0; baseB = OFF_P + bq*84 + 1; baseC = OFF_S + bq*52 + 1; }
    else if (o == 2){ baseA = OFF_P + bq*84 + 2; baseB = OFF_P + bq*84 + 3; baseC = OFF_S + bq*52 + 2; }
    else            { baseA = OFF_P + bq*84 + 4; baseB = OFF_D + lane;      baseC = OFF_D + lane; }
  }
  const int strA = (o == 0) ? 1 : 5;
  const int strB = (o == 0) ? 3 : ((o == 3) ? 0 : 5);
  const int strC = (o == 1 || o == 2) ? 3 : 0;

  for (int c0 = 0; c0 < H_STEPS; c0 += CHUNK){
    // ---- stage input chunk: 64 float4 per array per wave (1 per lane)
    {
      int bw = lane >> 2, sub = lane & 3;
      int gb = wbase + bw;
      vf4 iv = nt_load4(gI + (size_t)gb*H_STEPS + c0 + sub*4);
      vf4 tv = nt_load4(gT + (size_t)gb*H_STEPS + c0 + sub*4);
      *(vf4*)&ws[OFF_I + bw*20 + sub*4] = iv;
      *(vf4*)&ws[OFF_T + bw*20 + sub*4] = tv;
    }
    __builtin_amdgcn_wave_barrier();

    // rotated ik/tk: LDS read issued one step ahead
    float ikc = ws[OFF_I + bq*20 + 0];
    float tkc = ws[OFF_T + bq*20 + 0];

    #pragma unroll 1
    for (int kk = 0; kk < CHUNK; ++kk){
      const float ik = ikc, tk = tkc;
      {
        int kn = (kk + 1 < CHUNK) ? kk + 1 : kk;
        ikc = ws[OFF_I + bq*20 + kn];
        tkc = ws[OFF_T + bq*20 + kn];
      }

      // ---- (1) index calc + ISSUE table loads (consumed after the MLP)
      float tq = fminf(fmaxf((tk - T_LO) * T_INV, 0.0f), 511.999f);
      int   ti = (int)tq; float tf = tq - (float)ti;
      float sq = fminf(soc * 128.0f, 127.999f);
      int   si = (int)sq; float sf = sq - (float)si;
      const float* c = tab + (size_t)((si*TN + ti) << 3);
      vf4 q00 = *(const vf4*)(c);
      vf4 q01 = *(const vf4*)(c + 8);
      vf4 q10 = *(const vf4*)(c + 8*TN);
      vf4 q11 = *(const vf4*)(c + 8*TN + 8);
      float e00 = c[4], e01 = c[12], e10 = c[8*TN + 4], e11 = c[8*TN + 12];

      // ---- (2) residual MLP, unit-pairs packed, weights in pinned VGPRs
      vf2 ra2 = splat2(0.0f);
      const vf2 vc1s = splat2(vcp.x), vc2s = splat2(vcp.y);
      const vf2 socs = splat2(soc), iks = splat2(ik), tks = splat2(tk);
      #pragma unroll
      for (int p = 0; p < 8; ++p){
        vf2 arg = vfma2(vc1s, Wv1[p],
                  vfma2(vc2s, Wv2[p],
                  vfma2(socs, Wsc[p],
                  vfma2(iks,  Wik[p],
                  vfma2(tks,  Wtk[p], Wbb[p])))));
        vf2 e; e.x = fexp2(arg.x); e.y = fexp2(arg.y);
        vf2 r = prcp2(e + 1.0f);
        ra2 = vfma2(r, Wo[p], ra2);
      }
      float ra = ra2.x + ra2.y;
      ra += __shfl_xor(ra, 1, 4);
      ra += __shfl_xor(ra, 2, 4);

      // ---- (3) bilinear interp, (R0,R1) and (C1,R2) packed; C2 scalar
      float R0, R1, C1, R2, C2;
      {
        vf2 a00 = mk2(q00.x, q00.y), a01 = mk2(q01.x, q01.y);
        vf2 a10 = mk2(q10.x, q10.y), a11 = mk2(q11.x, q11.y);
        vf2 b00 = mk2(q00.z, q00.w), b01 = mk2(q01.z, q01.w);
        vf2 b10 = mk2(q10.z, q10.w), b11 = mk2(q11.z, q11.w);
        const vf2 tfs = splat2(tf), sfs = splat2(sf);
        vf2 v0 = vfma2(tfs, a01 - a00, a00);
        vf2 v1 = vfma2(tfs, a11 - a10, a10);
        vf2 RA = vfma2(sfs, v1 - v0, v0);          // {R0, R1}
        v0 = vfma2(tfs, b01 - b00, b00);
        v1 = vfma2(tfs, b11 - b10, b10);
        vf2 RB = vfma2(sfs, v1 - v0, v0);          // {C1, R2}
        float s0 = fmaf(tf, e01 - e00, e00);
        float s1 = fmaf(tf, e11 - e10, e10);
        C2 = fmaf(sf, s1 - s0, s0);
        R0 = RA.x; R1 = RA.y; C1 = RB.x; R2 = RB.y;
      }

      const float res = fmaf(-2.0f, ra, rb) * 0.01f;
      const float ocv = fmaf(1.2f, soc, 3.0f) - 0.4f * fexp2(-17.312340490667562f * soc);
      const float Vp  = ocv - R0 * ik - vcp.x - vcp.y + res;

      // ---- stage outputs for step k (pre-update state), R1 role split
      {
        float vA = (o==0) ? Vp    : (o==1) ? R0 : (o==2) ? C1 : C2;
        float vB = (o==0) ? vcp.x : (o==1) ? R1 : R2;
        float vC = (o==1) ? vcp.y : soc;
        ws[baseA + kk*strA] = vA;
        ws[baseB + kk*strB] = vB;
        ws[baseC + kk*strC] = vC;
      }

      // ---- RK4 folded: vc += (A - K*vc) * phi(K), phi = 1-K/2+K^2/6-K^3/24
      {
        vf2 iC = prcp2(mk2(C1, C2));
        vf2 A  = splat2(ik) * iC;
        vf2 K  = prcp2(mk2(R1 * C1, R2 * C2));
        vf2 phi = vfma2(K, vfma2(K, vfma2(K, splat2(-1.0f/24.0f), splat2(1.0f/6.0f)),
                                 splat2(-0.5f)), splat2(1.0f));
        vf2 k1 = vfma2(-K, vcp, A);
        vcp = vfma2(k1, phi, vcp);
      }

      soc = soc - ik * (1.0f/10800.0f);
      soc = fminf(fmaxf(soc, 0.0f), 1.0f);
    }
    __builtin_amdgcn_wave_barrier();

    // ---- writeback (non-temporal, contiguous per battery)
    {
      int bw = lane >> 2, sub = lane & 3;
      vf4 v = *(vf4*)&ws[OFF_V + bw*20 + sub*4];
      nt_store4(gV + (size_t)(wbase + bw)*H_STEPS + c0 + sub*4, v);
    }
    #pragma unroll
    for (int r = 0; r < 5; ++r){
      int s = lane + r*64;
      int bw = s / 20, sub = s % 20;
      vf4 v = *(vf4*)&ws[OFF_P + bw*84 + sub*4];
      nt_store4(gP + (size_t)(wbase + bw)*H_STEPS*5 + (size_t)c0*5 + sub*4, v);
    }
    #pragma unroll
    for (int r = 0; r < 3; ++r){
      int s = lane + r*64;
      int bw = s / 12, sub = s % 12;
      vf4 v = *(vf4*)&ws[OFF_S + bw*52 + sub*4];
      nt_store4(gS + (size_t)(wbase + bw)*H_STEPS*3 + (size_t)c0*3 + sub*4, v);
    }
    __builtin_amdgcn_wave_barrier();
  }
}

extern "C" void kernel_launch(void* const* d_in, const int* in_sizes, int n_in,
                              void* d_out, int out_size, void* d_ws, size_t ws_size,
                              hipStream_t stream)
{
  // setup_inputs order: V, I, Tz, soc0, W1, b1, W2, b2, Wr1, br1, Wr2, br2
  const float* gI   = (const float*)d_in[1];
  const float* gT   = (const float*)d_in[2];
  const float* gs0  = (const float*)d_in[3];
  const float* gW1  = (const float*)d_in[4];
  const float* gb1  = (const float*)d_in[5];
  const float* gW2  = (const float*)d_in[6];
  const float* gb2  = (const float*)d_in[7];
  const float* gWr1 = (const float*)d_in[8];
  const float* gbr1 = (const float*)d_in[9];
  const float* gWr2 = (const float*)d_in[10];
  const float* gbr2 = (const float*)d_in[11];

  float* gV = (float*)d_out;                                  // (B,H)
  float* gP = gV + (size_t)B_TOT * H_STEPS;                   // (B,H,5)
  float* gS = gP + (size_t)B_TOT * H_STEPS * 5;               // (B,H,3)

  float* tab = (float*)d_ws;   // 129*513*8 floats = 2.12MB of workspace

  {
    int cells = SN * TN;
    dim3 bgrid((cells + 255) / 256), bblock(256);
    hipLaunchKernelGGL(build_tab_kernel, bgrid, bblock, 0, stream,
                       gW1, gb1, gW2, gb2, tab);
  }
  dim3 grid(B_TOT / 64);   // T=4,G=1: 16 bat/wave, 512 blocks, 2 waves/SIMD
  dim3 block(256);
  hipLaunchKernelGGL(dcir_node_kernel, grid, block, 0, stream,
                     gI, gT, gs0, gWr1, gbr1, gWr2, gbr2, tab,
                     gV, gP, gS);
}